// Round 1
// baseline (623.124 us; speedup 1.0000x reference)
//
#include <hip/hip_runtime.h>
#include <math.h>

#define EPSF 1e-5f

// ---------------------------------------------------------------------------
// Depthwise 3x3 conv (SAME, stride 1), optional inference-BN applied to input.
// X: [B*C, 64, 64] per-channel planes. DW: [C,9]. Out same layout.
// grid (B*C, 4), block 256: each block does 16 rows.
// ---------------------------------------------------------------------------
template<bool BN>
__global__ __launch_bounds__(256) void dwconv_k(
    const float* __restrict__ X, const float* __restrict__ DW,
    const float* __restrict__ g, const float* __restrict__ be,
    const float* __restrict__ mn, const float* __restrict__ vr,
    float* __restrict__ Out)
{
    int bc = blockIdx.x;
    int c  = bc & 255;
    float inv = 1.f, ad = 0.f;
    if (BN) {
        inv = g[c] * rsqrtf(vr[c] + EPSF);
        ad  = be[c] - mn[c] * inv;
    }
    float w[9];
#pragma unroll
    for (int i = 0; i < 9; ++i) w[i] = DW[c * 9 + i];
    const float* Xb = X + (size_t)bc * 4096;
    float* Ob = Out + (size_t)bc * 4096;
    int ybase = blockIdx.y * 16;
#pragma unroll
    for (int it = 0; it < 4; ++it) {
        int p  = it * 256 + threadIdx.x;
        int y  = ybase + (p >> 6);
        int xx = p & 63;
        float s = 0.f;
#pragma unroll
        for (int ky = 0; ky < 3; ++ky) {
            int iy = y + ky - 1;
            if ((unsigned)iy < 64u) {
#pragma unroll
                for (int kx = 0; kx < 3; ++kx) {
                    int ix = xx + kx - 1;
                    if ((unsigned)ix < 64u) {
                        float v = Xb[iy * 64 + ix];
                        if (BN) v = v * inv + ad;
                        s += w[ky * 3 + kx] * v;
                    }
                }
            }
        }
        Ob[y * 64 + xx] = s;
    }
}

// ---------------------------------------------------------------------------
// Bilinear align_corners=True resize 64x64 -> 16x16 per channel plane.
// grid (B*C), block 256 (one thread per output pixel).
// ---------------------------------------------------------------------------
__global__ __launch_bounds__(256) void interp_k(
    const float* __restrict__ T, float* __restrict__ R)
{
    int bc = blockIdx.x;
    const float* Tb = T + (size_t)bc * 4096;
    int p  = threadIdx.x;
    int oy = p >> 4, ox = p & 15;
    const float st = 63.0f / 15.0f;
    float fy = oy * st, fx = ox * st;
    int y0 = (int)floorf(fy); int y1 = min(y0 + 1, 63); float wy = fy - (float)y0;
    int x0 = (int)floorf(fx); int x1 = min(x0 + 1, 63); float wx = fx - (float)x0;
    float v00 = Tb[y0 * 64 + x0], v01 = Tb[y0 * 64 + x1];
    float v10 = Tb[y1 * 64 + x0], v11 = Tb[y1 * 64 + x1];
    R[(size_t)bc * 256 + p] =
        (1.f - wy) * ((1.f - wx) * v00 + wx * v01) +
        wy         * ((1.f - wx) * v10 + wx * v11);
}

// ---------------------------------------------------------------------------
// Tiled fp32 GEMM: Out[b][n][m] = sum_k W[n][k] * A[b][k][m]  (+ epilogues)
// MODE 0: plain.  MODE 1: += X (same index).  MODE 2: A'=relu(bn(A)), += X.
// BM=BN=64, BK=16, 256 threads, 4x4 micro-tile.
// grid (M/64, N/64, B)
// ---------------------------------------------------------------------------
template<int MODE>
__global__ __launch_bounds__(256) void gemm_k(
    const float* __restrict__ A, const float* __restrict__ W,
    float* __restrict__ Out, const float* __restrict__ X,
    const float* __restrict__ g, const float* __restrict__ be,
    const float* __restrict__ mn, const float* __restrict__ vr,
    int M, int K, int Ntot)
{
    __shared__ float As[16][68];
    __shared__ float Ws[16][68];
    int b  = blockIdx.z;
    int m0 = blockIdx.x * 64;
    int n0 = blockIdx.y * 64;
    const float* Ab = A + (size_t)b * K * M;
    int tid = threadIdx.x;
    int tx = tid & 15, ty = tid >> 4;
    float acc[4][4] = {};
    for (int k0 = 0; k0 < K; k0 += 16) {
#pragma unroll
        for (int it = 0; it < 4; ++it) {
            int row = (tid >> 6) + it * 4;   // k within tile
            int col = tid & 63;              // m within tile
            float v = Ab[(size_t)(k0 + row) * M + m0 + col];
            if (MODE == 2) {
                int chn = k0 + row;
                float i2 = g[chn] * rsqrtf(vr[chn] + EPSF);
                float a2 = be[chn] - mn[chn] * i2;
                v = fmaxf(v * i2 + a2, 0.f);
            }
            As[row][col] = v;
        }
#pragma unroll
        for (int it = 0; it < 4; ++it) {
            int nn = (tid >> 4) + it * 16;   // n within tile
            int kk = tid & 15;               // k within tile
            Ws[kk][nn] = W[(size_t)(n0 + nn) * K + k0 + kk];
        }
        __syncthreads();
#pragma unroll
        for (int kk = 0; kk < 16; ++kk) {
            float4 a4 = *(const float4*)&As[kk][tx * 4];
            float4 w4 = *(const float4*)&Ws[kk][ty * 4];
            float aa[4] = {a4.x, a4.y, a4.z, a4.w};
            float wa[4] = {w4.x, w4.y, w4.z, w4.w};
#pragma unroll
            for (int i = 0; i < 4; ++i)
#pragma unroll
                for (int j = 0; j < 4; ++j)
                    acc[i][j] += wa[i] * aa[j];
        }
        __syncthreads();
    }
    size_t ob = (size_t)b * Ntot * M;
#pragma unroll
    for (int i = 0; i < 4; ++i) {
        int n = n0 + ty * 4 + i;
        size_t base = ob + (size_t)n * M + m0 + tx * 4;
        float4 r = make_float4(acc[i][0], acc[i][1], acc[i][2], acc[i][3]);
        if (MODE >= 1) {
            float4 xv = *(const float4*)&X[base];
            r.x += xv.x; r.y += xv.y; r.z += xv.z; r.w += xv.w;
        }
        *(float4*)&Out[base] = r;
    }
}

// ---------------------------------------------------------------------------
// Fused attention: per (batch, head, 256-row chunk) block.
// Q: [B,256,4096] NCHW (channel c = d*8+h). KV: [B,512,256] (k: cc<256, v: cc>=256).
// rel: [961,8]. O: [B,256,4096].
// Online softmax per thread (one q row), K/V staged in LDS.
// ---------------------------------------------------------------------------
__global__ __launch_bounds__(256) void attn_k(
    const float* __restrict__ Q, const float* __restrict__ KV,
    const float* __restrict__ rel, float* __restrict__ O)
{
    extern __shared__ float sm[];
    float* Ks = sm;               // [256][33]
    float* Vs = sm + 256 * 33;    // [256][33]
    int b = blockIdx.z, h = blockIdx.y, chk = blockIdx.x;
    int tid = threadIdx.x;
    const float* kvb = KV + (size_t)b * 512 * 256;
    for (int idx = tid; idx < 256 * 32; idx += 256) {
        int j = idx & 255, d = idx >> 8;
        Ks[j * 33 + d] = kvb[(d * 8 + h) * 256 + j];
        Vs[j * 33 + d] = kvb[(256 + d * 8 + h) * 256 + j];
    }
    __syncthreads();

    int r  = chk * 256 + tid;          // hw row index 0..4095
    int y  = r >> 6, xx = r & 63;
    int ay = y >> 2, ax = xx >> 2;     // reduced 16x16 coords of query
    const float* Qb = Q + (size_t)b * 256 * 4096;
    float q[32];
#pragma unroll
    for (int d = 0; d < 32; ++d) q[d] = Qb[(size_t)(d * 8 + h) * 4096 + r];

    const float SCALE = 0.17677669529663687f;  // 32^-0.5
    float m = -1e30f, l = 0.f;
    float acc[32] = {};
    for (int j = 0; j < 256; ++j) {
        int by = j >> 4, bx = j & 15;
        int idx = (ay - by + 15) * 31 + (ax - bx + 15);
        float bias = rel[idx * 8 + h];
        float s = 0.f;
#pragma unroll
        for (int d = 0; d < 32; ++d) s += q[d] * Ks[j * 33 + d];
        s = (s + bias) * SCALE;
        if (s > m) {
            float f = __expf(m - s);
            l *= f;
#pragma unroll
            for (int d = 0; d < 32; ++d) acc[d] *= f;
            m = s;
        }
        float p = __expf(s - m);
        l += p;
#pragma unroll
        for (int d = 0; d < 32; ++d) acc[d] += p * Vs[j * 33 + d];
    }
    float rl = 1.f / l;
    float* Ob = O + (size_t)b * 256 * 4096;
#pragma unroll
    for (int d = 0; d < 32; ++d)
        Ob[(size_t)(d * 8 + h) * 4096 + r] = acc[d] * rl;
}

// ---------------------------------------------------------------------------
extern "C" void kernel_launch(void* const* d_in, const int* in_sizes, int n_in,
                              void* d_out, int out_size, void* d_ws, size_t ws_size,
                              hipStream_t stream)
{
    const float* x       = (const float*)d_in[0];
    const float* bn1_g   = (const float*)d_in[1];
    const float* bn1_b   = (const float*)d_in[2];
    const float* bn1_m   = (const float*)d_in[3];
    const float* bn1_v   = (const float*)d_in[4];
    const float* qkv_dw  = (const float*)d_in[5];
    const float* qkv_pw  = (const float*)d_in[6];
    const float* out_dw  = (const float*)d_in[7];
    const float* out_pw  = (const float*)d_in[8];
    const float* rel     = (const float*)d_in[9];
    const float* bn2_g   = (const float*)d_in[10];
    const float* bn2_b   = (const float*)d_in[11];
    const float* bn2_m   = (const float*)d_in[12];
    const float* bn2_v   = (const float*)d_in[13];
    const float* mlp_w   = (const float*)d_in[14];
    float* out = (float*)d_out;

    float* ws = (float*)d_ws;
    float* t   = ws;                          // 8M floats   (BUF0: t / o / a)
    float* q   = ws + (size_t)8 * 1024 * 1024; // 8M floats  (BUF1: q / t2)
    float* tr  = ws + (size_t)16 * 1024 * 1024; // 524288
    float* kv  = tr + 524288;                  // 1048576
    float* o   = t;
    float* t2  = q;
    float* a   = t;

    // 1. t = dwconv3(bn1(x))
    dwconv_k<true><<<dim3(2048, 4), 256, 0, stream>>>(
        x, qkv_dw, bn1_g, bn1_b, bn1_m, bn1_v, t);

    // 2. q = qkv_pw[0:256] * t     [B,256,4096]
    gemm_k<0><<<dim3(64, 4, 8), 256, 0, stream>>>(
        t, qkv_pw, q, nullptr, nullptr, nullptr, nullptr, nullptr,
        4096, 256, 256);

    // 3. tr = interp(t) -> 16x16
    interp_k<<<dim3(2048), 256, 0, stream>>>(t, tr);

    // 4. kv = qkv_pw[256:768] * tr   [B,512,256]
    gemm_k<0><<<dim3(4, 8, 8), 256, 0, stream>>>(
        tr, qkv_pw + 256 * 256, kv, nullptr, nullptr, nullptr, nullptr, nullptr,
        256, 256, 512);

    // 5. o = attention(q, kv, rel)   [B,256,4096]   (overwrites t)
    attn_k<<<dim3(16, 8, 8), 256, 2 * 256 * 33 * sizeof(float), stream>>>(
        q, kv, rel, o);

    // 6. t2 = dwconv3(o)            (overwrites q)
    dwconv_k<false><<<dim3(2048, 4), 256, 0, stream>>>(
        o, out_dw, nullptr, nullptr, nullptr, nullptr, t2);

    // 7. a = out_pw * t2 + x        (overwrites o)
    gemm_k<1><<<dim3(64, 4, 8), 256, 0, stream>>>(
        t2, out_pw, a, x, nullptr, nullptr, nullptr, nullptr,
        4096, 256, 256);

    // 8. out = mlp_w * relu(bn2(a)) + a
    gemm_k<2><<<dim3(64, 4, 8), 256, 0, stream>>>(
        a, mlp_w, out, a, bn2_g, bn2_b, bn2_m, bn2_v,
        4096, 256, 256);
}

// Round 2
// 348.747 us; speedup vs baseline: 1.7868x; 1.7868x over previous
//
#include <hip/hip_runtime.h>
#include <math.h>

#define EPSF 1e-5f

typedef float f32x4 __attribute__((ext_vector_type(4)));
typedef short short8 __attribute__((ext_vector_type(8)));

static __device__ __forceinline__ unsigned short f2bf(float f) {
    unsigned u = __float_as_uint(f);
    u = (u + 0x7FFF + ((u >> 16) & 1)) >> 16;
    return (unsigned short)u;
}

// ---------------------------------------------------------------------------
// Depthwise 3x3 conv (SAME, stride 1), optional inference-BN applied to input.
// ---------------------------------------------------------------------------
template<bool BN>
__global__ __launch_bounds__(256) void dwconv_k(
    const float* __restrict__ X, const float* __restrict__ DW,
    const float* __restrict__ g, const float* __restrict__ be,
    const float* __restrict__ mn, const float* __restrict__ vr,
    float* __restrict__ Out)
{
    int bc = blockIdx.x;
    int c  = bc & 255;
    float inv = 1.f, ad = 0.f;
    if (BN) {
        inv = g[c] * rsqrtf(vr[c] + EPSF);
        ad  = be[c] - mn[c] * inv;
    }
    float w[9];
#pragma unroll
    for (int i = 0; i < 9; ++i) w[i] = DW[c * 9 + i];
    const float* Xb = X + (size_t)bc * 4096;
    float* Ob = Out + (size_t)bc * 4096;
    int ybase = blockIdx.y * 16;
#pragma unroll
    for (int it = 0; it < 4; ++it) {
        int p  = it * 256 + threadIdx.x;
        int y  = ybase + (p >> 6);
        int xx = p & 63;
        float s = 0.f;
#pragma unroll
        for (int ky = 0; ky < 3; ++ky) {
            int iy = y + ky - 1;
            if ((unsigned)iy < 64u) {
#pragma unroll
                for (int kx = 0; kx < 3; ++kx) {
                    int ix = xx + kx - 1;
                    if ((unsigned)ix < 64u) {
                        float v = Xb[iy * 64 + ix];
                        if (BN) v = v * inv + ad;
                        s += w[ky * 3 + kx] * v;
                    }
                }
            }
        }
        Ob[y * 64 + xx] = s;
    }
}

// ---------------------------------------------------------------------------
// Bilinear align_corners=True resize 64x64 -> 16x16 per channel plane.
// ---------------------------------------------------------------------------
__global__ __launch_bounds__(256) void interp_k(
    const float* __restrict__ T, float* __restrict__ R)
{
    int bc = blockIdx.x;
    const float* Tb = T + (size_t)bc * 4096;
    int p  = threadIdx.x;
    int oy = p >> 4, ox = p & 15;
    const float st = 63.0f / 15.0f;
    float fy = oy * st, fx = ox * st;
    int y0 = (int)floorf(fy); int y1 = min(y0 + 1, 63); float wy = fy - (float)y0;
    int x0 = (int)floorf(fx); int x1 = min(x0 + 1, 63); float wx = fx - (float)x0;
    float v00 = Tb[y0 * 64 + x0], v01 = Tb[y0 * 64 + x1];
    float v10 = Tb[y1 * 64 + x0], v11 = Tb[y1 * 64 + x1];
    R[(size_t)bc * 256 + p] =
        (1.f - wy) * ((1.f - wx) * v00 + wx * v01) +
        wy         * ((1.f - wx) * v10 + wx * v11);
}

// ---------------------------------------------------------------------------
// Tiled fp32 GEMM: Out[b][n][m] = sum_k W[n][k] * A[b][k][m]  (+ epilogues)
// ---------------------------------------------------------------------------
template<int MODE>
__global__ __launch_bounds__(256) void gemm_k(
    const float* __restrict__ A, const float* __restrict__ W,
    float* __restrict__ Out, const float* __restrict__ X,
    const float* __restrict__ g, const float* __restrict__ be,
    const float* __restrict__ mn, const float* __restrict__ vr,
    int M, int K, int Ntot)
{
    __shared__ float As[16][68];
    __shared__ float Ws[16][68];
    int b  = blockIdx.z;
    int m0 = blockIdx.x * 64;
    int n0 = blockIdx.y * 64;
    const float* Ab = A + (size_t)b * K * M;
    int tid = threadIdx.x;
    int tx = tid & 15, ty = tid >> 4;
    float acc[4][4] = {};
    for (int k0 = 0; k0 < K; k0 += 16) {
#pragma unroll
        for (int it = 0; it < 4; ++it) {
            int row = (tid >> 6) + it * 4;
            int col = tid & 63;
            float v = Ab[(size_t)(k0 + row) * M + m0 + col];
            if (MODE == 2) {
                int chn = k0 + row;
                float i2 = g[chn] * rsqrtf(vr[chn] + EPSF);
                float a2 = be[chn] - mn[chn] * i2;
                v = fmaxf(v * i2 + a2, 0.f);
            }
            As[row][col] = v;
        }
#pragma unroll
        for (int it = 0; it < 4; ++it) {
            int nn = (tid >> 4) + it * 16;
            int kk = tid & 15;
            Ws[kk][nn] = W[(size_t)(n0 + nn) * K + k0 + kk];
        }
        __syncthreads();
#pragma unroll
        for (int kk = 0; kk < 16; ++kk) {
            float4 a4 = *(const float4*)&As[kk][tx * 4];
            float4 w4 = *(const float4*)&Ws[kk][ty * 4];
            float aa[4] = {a4.x, a4.y, a4.z, a4.w};
            float wa[4] = {w4.x, w4.y, w4.z, w4.w};
#pragma unroll
            for (int i = 0; i < 4; ++i)
#pragma unroll
                for (int j = 0; j < 4; ++j)
                    acc[i][j] += wa[i] * aa[j];
        }
        __syncthreads();
    }
    size_t ob = (size_t)b * Ntot * M;
#pragma unroll
    for (int i = 0; i < 4; ++i) {
        int n = n0 + ty * 4 + i;
        size_t base = ob + (size_t)n * M + m0 + tx * 4;
        float4 r = make_float4(acc[i][0], acc[i][1], acc[i][2], acc[i][3]);
        if (MODE >= 1) {
            float4 xv = *(const float4*)&X[base];
            r.x += xv.x; r.y += xv.y; r.z += xv.z; r.w += xv.w;
        }
        *(float4*)&Out[base] = r;
    }
}

// ---------------------------------------------------------------------------
// MFMA attention. Per block: one (b,h), 512 q-rows. 512 threads = 8 waves,
// each wave owns 64 rows = 4 m-tiles of 16. K=32 (=DH) per mfma.
// Q: [B,256ch,4096] (ch = d*8+h), KV: [B,512,256], rel: [961,8], O: [B,256,4096].
// ---------------------------------------------------------------------------
__global__ __launch_bounds__(512) void attn_mfma_k(
    const float* __restrict__ Q, const float* __restrict__ KV,
    const float* __restrict__ rel, float* __restrict__ O)
{
    __shared__ unsigned short Ks[256 * 40];     // [key][dim], pad 40
    __shared__ unsigned short Vt[32 * 264];     // [dim][key], pad 264
    __shared__ unsigned short Pw[8 * 16 * 264]; // per-wave P tile
    __shared__ float rels[961];

    int b = blockIdx.z, h = blockIdx.y, chunk = blockIdx.x;
    int tid = threadIdx.x;
    const float* kvb = KV + (size_t)b * 512 * 256;

    // stage K (bf16): Ks[key][dim]
    for (int idx = tid; idx < 256 * 16; idx += 512) {
        int r = idx & 255, d = (idx >> 8) * 2;
        float a0 = kvb[(size_t)(d * 8 + h) * 256 + r];
        float a1 = kvb[(size_t)((d + 1) * 8 + h) * 256 + r];
        unsigned pk = (unsigned)f2bf(a0) | ((unsigned)f2bf(a1) << 16);
        *(unsigned*)&Ks[r * 40 + d] = pk;
    }
    // stage V transposed (bf16): Vt[dim][key]
    for (int idx = tid; idx < 32 * 128; idx += 512) {
        int d = idx >> 7, k2 = (idx & 127) * 2;
        float2 v2 = *(const float2*)&kvb[(size_t)(256 + d * 8 + h) * 256 + k2];
        unsigned pk = (unsigned)f2bf(v2.x) | ((unsigned)f2bf(v2.y) << 16);
        *(unsigned*)&Vt[d * 264 + k2] = pk;
    }
    for (int idx = tid; idx < 961; idx += 512) rels[idx] = rel[idx * 8 + h];
    __syncthreads();

    int w = tid >> 6, lane = tid & 63;
    int lg = lane >> 4, lc = lane & 15;
    unsigned short* Pws = Pw + w * 16 * 264;

    // hoisted K/V fragments (reused across 4 m-tiles)
    short8 kf[16], vf[16];
#pragma unroll
    for (int kt = 0; kt < 16; ++kt)
        kf[kt] = *(const short8*)&Ks[(kt * 16 + lc) * 40 + lg * 8];
#pragma unroll
    for (int f = 0; f < 16; ++f) {
        int ks = f >> 1, nt = f & 1;
        vf[f] = *(const short8*)&Vt[(nt * 16 + lc) * 264 + ks * 32 + lg * 8];
    }

    const float SCALE = 0.17677669529663687f;  // 32^-0.5
    const float* Qb = Q + (size_t)b * 256 * 4096;
    float* Ob = O + (size_t)b * 256 * 4096;
    int rw = chunk * 512 + w * 64;

    for (int mt = 0; mt < 4; ++mt) {
        int rbase = rw + mt * 16;
        // Q A-fragment straight from global (each element read once)
        int r_a = rbase + lc;
        short8 qf;
#pragma unroll
        for (int j = 0; j < 8; ++j) {
            float qv = Qb[(size_t)((lg * 8 + j) * 8 + h) * 4096 + r_a];
            qf[j] = (short)f2bf(qv);
        }

        f32x4 sacc[16];
#pragma unroll
        for (int kt = 0; kt < 16; ++kt) {
            f32x4 z = {0.f, 0.f, 0.f, 0.f};
            sacc[kt] = __builtin_amdgcn_mfma_f32_16x16x32_bf16(qf, kf[kt], z, 0, 0, 0);
        }

        // bias + scale; rows handled by this lane: rbase + lg*4 + reg
        int ibase[4];
#pragma unroll
        for (int reg = 0; reg < 4; ++reg) {
            int r = rbase + lg * 4 + reg;
            int ay = r >> 8, ax = (r >> 2) & 15;
            ibase[reg] = (ay + 15) * 31 + ax + 15 - lc;
        }
        float mx[4] = {-1e30f, -1e30f, -1e30f, -1e30f};
#pragma unroll
        for (int kt = 0; kt < 16; ++kt) {
            int ib = -kt * 31;
#pragma unroll
            for (int reg = 0; reg < 4; ++reg) {
                float v = (sacc[kt][reg] + rels[ibase[reg] + ib]) * SCALE;
                sacc[kt][reg] = v;
                mx[reg] = fmaxf(mx[reg], v);
            }
        }
#pragma unroll
        for (int off = 1; off < 16; off <<= 1) {
#pragma unroll
            for (int reg = 0; reg < 4; ++reg)
                mx[reg] = fmaxf(mx[reg], __shfl_xor(mx[reg], off));
        }
        float ls[4] = {0.f, 0.f, 0.f, 0.f};
#pragma unroll
        for (int kt = 0; kt < 16; ++kt) {
#pragma unroll
            for (int reg = 0; reg < 4; ++reg) {
                float p = __expf(sacc[kt][reg] - mx[reg]);
                ls[reg] += p;
                Pws[(lg * 4 + reg) * 264 + kt * 16 + lc] = f2bf(p);
            }
        }
#pragma unroll
        for (int off = 1; off < 16; off <<= 1) {
#pragma unroll
            for (int reg = 0; reg < 4; ++reg)
                ls[reg] += __shfl_xor(ls[reg], off);
        }

        // PV
        f32x4 o0 = {0.f, 0.f, 0.f, 0.f}, o1 = {0.f, 0.f, 0.f, 0.f};
#pragma unroll
        for (int ks = 0; ks < 8; ++ks) {
            short8 pf = *(const short8*)&Pws[lc * 264 + ks * 32 + lg * 8];
            o0 = __builtin_amdgcn_mfma_f32_16x16x32_bf16(pf, vf[ks * 2 + 0], o0, 0, 0, 0);
            o1 = __builtin_amdgcn_mfma_f32_16x16x32_bf16(pf, vf[ks * 2 + 1], o1, 0, 0, 0);
        }

#pragma unroll
        for (int reg = 0; reg < 4; ++reg) {
            float rl = 1.f / ls[reg];
            int r = rbase + lg * 4 + reg;
            Ob[(size_t)(lc * 8 + h) * 4096 + r]        = o0[reg] * rl;
            Ob[(size_t)((16 + lc) * 8 + h) * 4096 + r] = o1[reg] * rl;
        }
    }
}

// ---------------------------------------------------------------------------
extern "C" void kernel_launch(void* const* d_in, const int* in_sizes, int n_in,
                              void* d_out, int out_size, void* d_ws, size_t ws_size,
                              hipStream_t stream)
{
    const float* x       = (const float*)d_in[0];
    const float* bn1_g   = (const float*)d_in[1];
    const float* bn1_b   = (const float*)d_in[2];
    const float* bn1_m   = (const float*)d_in[3];
    const float* bn1_v   = (const float*)d_in[4];
    const float* qkv_dw  = (const float*)d_in[5];
    const float* qkv_pw  = (const float*)d_in[6];
    const float* out_dw  = (const float*)d_in[7];
    const float* out_pw  = (const float*)d_in[8];
    const float* rel     = (const float*)d_in[9];
    const float* bn2_g   = (const float*)d_in[10];
    const float* bn2_b   = (const float*)d_in[11];
    const float* bn2_m   = (const float*)d_in[12];
    const float* bn2_v   = (const float*)d_in[13];
    const float* mlp_w   = (const float*)d_in[14];
    float* out = (float*)d_out;

    float* ws = (float*)d_ws;
    float* t   = ws;                           // BUF0: t / o / a
    float* q   = ws + (size_t)8 * 1024 * 1024; // BUF1: q / t2
    float* tr  = ws + (size_t)16 * 1024 * 1024;
    float* kv  = tr + 524288;
    float* o   = t;
    float* t2  = q;
    float* a   = t;

    // 1. t = dwconv3(bn1(x))
    dwconv_k<true><<<dim3(2048, 4), 256, 0, stream>>>(
        x, qkv_dw, bn1_g, bn1_b, bn1_m, bn1_v, t);

    // 2. q = qkv_pw[0:256] * t     [B,256,4096]
    gemm_k<0><<<dim3(64, 4, 8), 256, 0, stream>>>(
        t, qkv_pw, q, nullptr, nullptr, nullptr, nullptr, nullptr,
        4096, 256, 256);

    // 3. tr = interp(t) -> 16x16
    interp_k<<<dim3(2048), 256, 0, stream>>>(t, tr);

    // 4. kv = qkv_pw[256:768] * tr   [B,512,256]
    gemm_k<0><<<dim3(4, 8, 8), 256, 0, stream>>>(
        tr, qkv_pw + 256 * 256, kv, nullptr, nullptr, nullptr, nullptr, nullptr,
        256, 256, 512);

    // 5. o = MFMA attention(q, kv, rel)   [B,256,4096]   (overwrites t)
    attn_mfma_k<<<dim3(8, 8, 8), 512, 0, stream>>>(q, kv, rel, o);

    // 6. t2 = dwconv3(o)            (overwrites q)
    dwconv_k<false><<<dim3(2048, 4), 256, 0, stream>>>(
        o, out_dw, nullptr, nullptr, nullptr, nullptr, t2);

    // 7. a = out_pw * t2 + x        (overwrites o)
    gemm_k<1><<<dim3(64, 4, 8), 256, 0, stream>>>(
        t2, out_pw, a, x, nullptr, nullptr, nullptr, nullptr,
        4096, 256, 256);

    // 8. out = mlp_w * relu(bn2(a)) + a
    gemm_k<2><<<dim3(64, 4, 8), 256, 0, stream>>>(
        a, mlp_w, out, a, bn2_g, bn2_b, bn2_m, bn2_v,
        4096, 256, 256);
}

// Round 3
// 198.437 us; speedup vs baseline: 3.1402x; 1.7575x over previous
//
#include <hip/hip_runtime.h>
#include <math.h>

#define EPSF 1e-5f

typedef float f32x4 __attribute__((ext_vector_type(4)));
typedef short short8 __attribute__((ext_vector_type(8)));
typedef short short4v __attribute__((ext_vector_type(4)));

static __device__ __forceinline__ unsigned short f2bf(float f) {
    unsigned u = __float_as_uint(f);
    u = (u + 0x7FFF + ((u >> 16) & 1)) >> 16;
    return (unsigned short)u;
}

// XOR-swizzle: spreads 8-byte granules of a row across banks; keeps 16B pairs.
static __device__ __forceinline__ int swz(int r) { return ((r ^ (r >> 2)) & 7) << 1; }

// ---------------------------------------------------------------------------
// Depthwise 3x3 conv (SAME, stride 1), optional inference-BN applied to input.
// ---------------------------------------------------------------------------
template<bool BN>
__global__ __launch_bounds__(256) void dwconv_k(
    const float* __restrict__ X, const float* __restrict__ DW,
    const float* __restrict__ g, const float* __restrict__ be,
    const float* __restrict__ mn, const float* __restrict__ vr,
    float* __restrict__ Out)
{
    int bc = blockIdx.x;
    int c  = bc & 255;
    float inv = 1.f, ad = 0.f;
    if (BN) {
        inv = g[c] * rsqrtf(vr[c] + EPSF);
        ad  = be[c] - mn[c] * inv;
    }
    float w[9];
#pragma unroll
    for (int i = 0; i < 9; ++i) w[i] = DW[c * 9 + i];
    const float* Xb = X + (size_t)bc * 4096;
    float* Ob = Out + (size_t)bc * 4096;
    int ybase = blockIdx.y * 16;
#pragma unroll
    for (int it = 0; it < 4; ++it) {
        int p  = it * 256 + threadIdx.x;
        int y  = ybase + (p >> 6);
        int xx = p & 63;
        float s = 0.f;
#pragma unroll
        for (int ky = 0; ky < 3; ++ky) {
            int iy = y + ky - 1;
            if ((unsigned)iy < 64u) {
#pragma unroll
                for (int kx = 0; kx < 3; ++kx) {
                    int ix = xx + kx - 1;
                    if ((unsigned)ix < 64u) {
                        float v = Xb[iy * 64 + ix];
                        if (BN) v = v * inv + ad;
                        s += w[ky * 3 + kx] * v;
                    }
                }
            }
        }
        Ob[y * 64 + xx] = s;
    }
}

// ---------------------------------------------------------------------------
// Bilinear align_corners=True resize 64x64 -> 16x16 per channel plane.
// ---------------------------------------------------------------------------
__global__ __launch_bounds__(256) void interp_k(
    const float* __restrict__ T, float* __restrict__ R)
{
    int bc = blockIdx.x;
    const float* Tb = T + (size_t)bc * 4096;
    int p  = threadIdx.x;
    int oy = p >> 4, ox = p & 15;
    const float st = 63.0f / 15.0f;
    float fy = oy * st, fx = ox * st;
    int y0 = (int)floorf(fy); int y1 = min(y0 + 1, 63); float wy = fy - (float)y0;
    int x0 = (int)floorf(fx); int x1 = min(x0 + 1, 63); float wx = fx - (float)x0;
    float v00 = Tb[y0 * 64 + x0], v01 = Tb[y0 * 64 + x1];
    float v10 = Tb[y1 * 64 + x0], v11 = Tb[y1 * 64 + x1];
    R[(size_t)bc * 256 + p] =
        (1.f - wy) * ((1.f - wx) * v00 + wx * v01) +
        wy         * ((1.f - wx) * v10 + wx * v11);
}

// ---------------------------------------------------------------------------
// bf16 MFMA GEMM: Out[b][n][m] = sum_k W[n][k] * A[b][k][m]  (K=256 fixed)
// MODE 0: plain. MODE 1: += X. MODE 2: A'=relu(bn(A)) (channel=k), += X.
// BM=BN=128, BK=64, 256 threads = 4 waves (2m x 2n), wave tile 64x64.
// A is [k][m]; staged to LDS as As[m][k] via in-register 4x4 transpose.
// W is [n][k]; staged once to Ws[n][k]. Both bf16, XOR-swizzled granules.
// grid (M/128, N/128, B)
// ---------------------------------------------------------------------------
template<int MODE>
__global__ __launch_bounds__(256) void mgemm_k(
    const float* __restrict__ A, const float* __restrict__ W,
    float* __restrict__ Out, const float* __restrict__ X,
    const float* __restrict__ g, const float* __restrict__ be,
    const float* __restrict__ mn, const float* __restrict__ vr,
    int M, int Ntot)
{
    __shared__ short Ws[128 * 256];
    __shared__ short As[128 * 64];
    int b = blockIdx.z, m0 = blockIdx.x * 128, n0 = blockIdx.y * 128;
    int tid = threadIdx.x;
    const float* Ab = A + (size_t)b * 256 * M;

    // stage W [n0..n0+127][0..255] -> Ws (bf16, swizzled)
#pragma unroll
    for (int it = 0; it < 32; ++it) {
        int idx = it * 256 + tid;
        int n = idx >> 6, kq = idx & 63;
        f32x4 w4 = *(const f32x4*)&W[(size_t)(n0 + n) * 256 + kq * 4];
        short4v pk = { (short)f2bf(w4[0]), (short)f2bf(w4[1]),
                       (short)f2bf(w4[2]), (short)f2bf(w4[3]) };
        *(short4v*)&Ws[n * 256 + ((kq ^ swz(n)) << 2)] = pk;
    }

    int mg = tid & 31, kg = tid >> 5;   // m0t = mg*4, k rows kg*4(+32)
    f32x4 rg[8];
    auto load_tile = [&](int k0) {
#pragma unroll
        for (int half = 0; half < 2; ++half) {
#pragma unroll
            for (int i = 0; i < 4; ++i) {
                int c = k0 + kg * 4 + half * 32 + i;
                f32x4 v = *(const f32x4*)&Ab[(size_t)c * M + m0 + mg * 4];
                if (MODE == 2) {
                    float iv = g[c] * rsqrtf(vr[c] + EPSF);
                    float ad = be[c] - mn[c] * iv;
#pragma unroll
                    for (int j = 0; j < 4; ++j) v[j] = fmaxf(v[j] * iv + ad, 0.f);
                }
                rg[half * 4 + i] = v;
            }
        }
    };
    load_tile(0);

    int w = tid >> 6, lane = tid & 63;
    int wm = w & 1, wn = w >> 1;
    int lg = lane >> 4, lc = lane & 15;
    f32x4 acc[4][4] = {};  // [nt][mt]

    for (int k0 = 0; k0 < 256; k0 += 64) {
        __syncthreads();
        // 4x4 register transpose -> As[m][k] (bf16, swizzled)
#pragma unroll
        for (int half = 0; half < 2; ++half) {
#pragma unroll
            for (int j = 0; j < 4; ++j) {
                int m = mg * 4 + j;
                short4v pk = { (short)f2bf(rg[half * 4 + 0][j]), (short)f2bf(rg[half * 4 + 1][j]),
                               (short)f2bf(rg[half * 4 + 2][j]), (short)f2bf(rg[half * 4 + 3][j]) };
                *(short4v*)&As[m * 64 + (((kg + half * 8) ^ swz(m)) << 2)] = pk;
            }
        }
        __syncthreads();
        if (k0 < 192) load_tile(k0 + 64);
#pragma unroll
        for (int ksl = 0; ksl < 2; ++ksl) {
            short8 wf[4], af[4];
            int gk = (k0 + ksl * 32 + lg * 8) >> 2;   // Ws granule (global k)
            int ga = (ksl * 32 + lg * 8) >> 2;        // As granule (local k)
#pragma unroll
            for (int nt = 0; nt < 4; ++nt) {
                int n = wn * 64 + nt * 16 + lc;
                wf[nt] = *(const short8*)&Ws[n * 256 + ((gk ^ swz(n)) << 2)];
            }
#pragma unroll
            for (int mt = 0; mt < 4; ++mt) {
                int m = wm * 64 + mt * 16 + lc;
                af[mt] = *(const short8*)&As[m * 64 + ((ga ^ swz(m)) << 2)];
            }
#pragma unroll
            for (int nt = 0; nt < 4; ++nt)
#pragma unroll
                for (int mt = 0; mt < 4; ++mt)
                    acc[nt][mt] = __builtin_amdgcn_mfma_f32_16x16x32_bf16(
                        wf[nt], af[mt], acc[nt][mt], 0, 0, 0);
        }
    }

    size_t ob = (size_t)b * Ntot * M;
#pragma unroll
    for (int nt = 0; nt < 4; ++nt) {
#pragma unroll
        for (int mt = 0; mt < 4; ++mt) {
#pragma unroll
            for (int reg = 0; reg < 4; ++reg) {
                int n = n0 + wn * 64 + nt * 16 + lg * 4 + reg;
                int m = m0 + wm * 64 + mt * 16 + lc;
                size_t addr = ob + (size_t)n * M + m;
                float v = acc[nt][mt][reg];
                if (MODE >= 1) v += X[addr];
                Out[addr] = v;
            }
        }
    }
}

// ---------------------------------------------------------------------------
// MFMA attention (unchanged from round 2).
// ---------------------------------------------------------------------------
__global__ __launch_bounds__(512) void attn_mfma_k(
    const float* __restrict__ Q, const float* __restrict__ KV,
    const float* __restrict__ rel, float* __restrict__ O)
{
    __shared__ unsigned short Ks[256 * 40];
    __shared__ unsigned short Vt[32 * 264];
    __shared__ unsigned short Pw[8 * 16 * 264];
    __shared__ float rels[961];

    int b = blockIdx.z, h = blockIdx.y, chunk = blockIdx.x;
    int tid = threadIdx.x;
    const float* kvb = KV + (size_t)b * 512 * 256;

    for (int idx = tid; idx < 256 * 16; idx += 512) {
        int r = idx & 255, d = (idx >> 8) * 2;
        float a0 = kvb[(size_t)(d * 8 + h) * 256 + r];
        float a1 = kvb[(size_t)((d + 1) * 8 + h) * 256 + r];
        unsigned pk = (unsigned)f2bf(a0) | ((unsigned)f2bf(a1) << 16);
        *(unsigned*)&Ks[r * 40 + d] = pk;
    }
    for (int idx = tid; idx < 32 * 128; idx += 512) {
        int d = idx >> 7, k2 = (idx & 127) * 2;
        float2 v2 = *(const float2*)&kvb[(size_t)(256 + d * 8 + h) * 256 + k2];
        unsigned pk = (unsigned)f2bf(v2.x) | ((unsigned)f2bf(v2.y) << 16);
        *(unsigned*)&Vt[d * 264 + k2] = pk;
    }
    for (int idx = tid; idx < 961; idx += 512) rels[idx] = rel[idx * 8 + h];
    __syncthreads();

    int w = tid >> 6, lane = tid & 63;
    int lg = lane >> 4, lc = lane & 15;
    unsigned short* Pws = Pw + w * 16 * 264;

    short8 kf[16], vf[16];
#pragma unroll
    for (int kt = 0; kt < 16; ++kt)
        kf[kt] = *(const short8*)&Ks[(kt * 16 + lc) * 40 + lg * 8];
#pragma unroll
    for (int f = 0; f < 16; ++f) {
        int ks = f >> 1, nt = f & 1;
        vf[f] = *(const short8*)&Vt[(nt * 16 + lc) * 264 + ks * 32 + lg * 8];
    }

    const float SCALE = 0.17677669529663687f;
    const float* Qb = Q + (size_t)b * 256 * 4096;
    float* Ob = O + (size_t)b * 256 * 4096;
    int rw = chunk * 512 + w * 64;

    for (int mt = 0; mt < 4; ++mt) {
        int rbase = rw + mt * 16;
        int r_a = rbase + lc;
        short8 qf;
#pragma unroll
        for (int j = 0; j < 8; ++j) {
            float qv = Qb[(size_t)((lg * 8 + j) * 8 + h) * 4096 + r_a];
            qf[j] = (short)f2bf(qv);
        }

        f32x4 sacc[16];
#pragma unroll
        for (int kt = 0; kt < 16; ++kt) {
            f32x4 z = {0.f, 0.f, 0.f, 0.f};
            sacc[kt] = __builtin_amdgcn_mfma_f32_16x16x32_bf16(qf, kf[kt], z, 0, 0, 0);
        }

        int ibase[4];
#pragma unroll
        for (int reg = 0; reg < 4; ++reg) {
            int r = rbase + lg * 4 + reg;
            int ay = r >> 8, ax = (r >> 2) & 15;
            ibase[reg] = (ay + 15) * 31 + ax + 15 - lc;
        }
        float mx[4] = {-1e30f, -1e30f, -1e30f, -1e30f};
#pragma unroll
        for (int kt = 0; kt < 16; ++kt) {
            int ib = -kt * 31;
#pragma unroll
            for (int reg = 0; reg < 4; ++reg) {
                float v = (sacc[kt][reg] + rels[ibase[reg] + ib]) * SCALE;
                sacc[kt][reg] = v;
                mx[reg] = fmaxf(mx[reg], v);
            }
        }
#pragma unroll
        for (int off = 1; off < 16; off <<= 1) {
#pragma unroll
            for (int reg = 0; reg < 4; ++reg)
                mx[reg] = fmaxf(mx[reg], __shfl_xor(mx[reg], off));
        }
        float ls[4] = {0.f, 0.f, 0.f, 0.f};
#pragma unroll
        for (int kt = 0; kt < 16; ++kt) {
#pragma unroll
            for (int reg = 0; reg < 4; ++reg) {
                float p = __expf(sacc[kt][reg] - mx[reg]);
                ls[reg] += p;
                Pws[(lg * 4 + reg) * 264 + kt * 16 + lc] = f2bf(p);
            }
        }
#pragma unroll
        for (int off = 1; off < 16; off <<= 1) {
#pragma unroll
            for (int reg = 0; reg < 4; ++reg)
                ls[reg] += __shfl_xor(ls[reg], off);
        }

        f32x4 o0 = {0.f, 0.f, 0.f, 0.f}, o1 = {0.f, 0.f, 0.f, 0.f};
#pragma unroll
        for (int ks = 0; ks < 8; ++ks) {
            short8 pf = *(const short8*)&Pws[lc * 264 + ks * 32 + lg * 8];
            o0 = __builtin_amdgcn_mfma_f32_16x16x32_bf16(pf, vf[ks * 2 + 0], o0, 0, 0, 0);
            o1 = __builtin_amdgcn_mfma_f32_16x16x32_bf16(pf, vf[ks * 2 + 1], o1, 0, 0, 0);
        }

#pragma unroll
        for (int reg = 0; reg < 4; ++reg) {
            float rl = 1.f / ls[reg];
            int r = rbase + lg * 4 + reg;
            Ob[(size_t)(lc * 8 + h) * 4096 + r]        = o0[reg] * rl;
            Ob[(size_t)((16 + lc) * 8 + h) * 4096 + r] = o1[reg] * rl;
        }
    }
}

// ---------------------------------------------------------------------------
extern "C" void kernel_launch(void* const* d_in, const int* in_sizes, int n_in,
                              void* d_out, int out_size, void* d_ws, size_t ws_size,
                              hipStream_t stream)
{
    const float* x       = (const float*)d_in[0];
    const float* bn1_g   = (const float*)d_in[1];
    const float* bn1_b   = (const float*)d_in[2];
    const float* bn1_m   = (const float*)d_in[3];
    const float* bn1_v   = (const float*)d_in[4];
    const float* qkv_dw  = (const float*)d_in[5];
    const float* qkv_pw  = (const float*)d_in[6];
    const float* out_dw  = (const float*)d_in[7];
    const float* out_pw  = (const float*)d_in[8];
    const float* rel     = (const float*)d_in[9];
    const float* bn2_g   = (const float*)d_in[10];
    const float* bn2_b   = (const float*)d_in[11];
    const float* bn2_m   = (const float*)d_in[12];
    const float* bn2_v   = (const float*)d_in[13];
    const float* mlp_w   = (const float*)d_in[14];
    float* out = (float*)d_out;

    float* ws = (float*)d_ws;
    float* t   = ws;                           // BUF0: t / o / a
    float* q   = ws + (size_t)8 * 1024 * 1024; // BUF1: q / t2
    float* tr  = ws + (size_t)16 * 1024 * 1024;
    float* kv  = tr + 524288;
    float* o   = t;
    float* t2  = q;
    float* a   = t;

    // 1. t = dwconv3(bn1(x))
    dwconv_k<true><<<dim3(2048, 4), 256, 0, stream>>>(
        x, qkv_dw, bn1_g, bn1_b, bn1_m, bn1_v, t);

    // 2. q = qkv_pw[0:256] * t     [B,256,4096]
    mgemm_k<0><<<dim3(32, 2, 8), 256, 0, stream>>>(
        t, qkv_pw, q, nullptr, nullptr, nullptr, nullptr, nullptr,
        4096, 256);

    // 3. tr = interp(t) -> 16x16
    interp_k<<<dim3(2048), 256, 0, stream>>>(t, tr);

    // 4. kv = qkv_pw[256:768] * tr   [B,512,256]
    mgemm_k<0><<<dim3(2, 4, 8), 256, 0, stream>>>(
        tr, qkv_pw + 256 * 256, kv, nullptr, nullptr, nullptr, nullptr, nullptr,
        256, 512);

    // 5. o = MFMA attention(q, kv, rel)   [B,256,4096]   (overwrites t)
    attn_mfma_k<<<dim3(8, 8, 8), 512, 0, stream>>>(q, kv, rel, o);

    // 6. t2 = dwconv3(o)            (overwrites q)
    dwconv_k<false><<<dim3(2048, 4), 256, 0, stream>>>(
        o, out_dw, nullptr, nullptr, nullptr, nullptr, t2);

    // 7. a = out_pw * t2 + x        (overwrites o)
    mgemm_k<1><<<dim3(32, 2, 8), 256, 0, stream>>>(
        t2, out_pw, a, x, nullptr, nullptr, nullptr, nullptr,
        4096, 256);

    // 8. out = mlp_w * relu(bn2(a)) + a
    mgemm_k<2><<<dim3(32, 2, 8), 256, 0, stream>>>(
        a, mlp_w, out, a, bn2_g, bn2_b, bn2_m, bn2_v,
        4096, 256);
}

// Round 4
// 148.881 us; speedup vs baseline: 4.1854x; 1.3329x over previous
//
#include <hip/hip_runtime.h>
#include <math.h>

#define EPSF 1e-5f

typedef float f32x4 __attribute__((ext_vector_type(4)));
typedef short short8 __attribute__((ext_vector_type(8)));
typedef short short4v __attribute__((ext_vector_type(4)));

static __device__ __forceinline__ unsigned short f2bf(float f) {
    unsigned u = __float_as_uint(f);
    u = (u + 0x7FFF + ((u >> 16) & 1)) >> 16;
    return (unsigned short)u;
}

// XOR-swizzle: spreads 8-byte granules of a row across banks; keeps 16B pairs.
static __device__ __forceinline__ int swz(int r) { return ((r ^ (r >> 2)) & 7) << 1; }

// ---------------------------------------------------------------------------
// Depthwise 3x3 conv (SAME), vectorized: each thread computes a 4x8 tile.
// Loads 6 rows x 4 float4 (zero-filled OOB), 288 FMA, 8 float4 stores.
// 2 planes per 256-thread block. grid(B*C/2).
// ---------------------------------------------------------------------------
template<bool BN>
__global__ __launch_bounds__(256) void dwconv_k(
    const float* __restrict__ X, const float* __restrict__ DW,
    const float* __restrict__ g, const float* __restrict__ be,
    const float* __restrict__ mn, const float* __restrict__ vr,
    float* __restrict__ Out)
{
    int tid = threadIdx.x;
    int plane = blockIdx.x * 2 + (tid >> 7);
    int c = plane & 255;
    float inv = 1.f, ad = 0.f;
    if (BN) {
        inv = g[c] * rsqrtf(vr[c] + EPSF);
        ad  = be[c] - mn[c] * inv;
    }
    float w[9];
#pragma unroll
    for (int i = 0; i < 9; ++i) w[i] = DW[c * 9 + i];
    const float* Xb = X + (size_t)plane * 4096;
    float* Ob = Out + (size_t)plane * 4096;
    int u  = tid & 127;
    int y0 = (u >> 3) * 4;
    int x0 = (u & 7) * 8;

    float r[6][16];
#pragma unroll
    for (int rr = 0; rr < 6; ++rr) {
        int yy = y0 + rr - 1;
        bool rv = (unsigned)yy < 64u;
#pragma unroll
        for (int gq = 0; gq < 4; ++gq) {
            int xx = x0 - 4 + gq * 4;
            f32x4 v = {0.f, 0.f, 0.f, 0.f};
            if (rv && (unsigned)xx < 64u) {
                v = *(const f32x4*)&Xb[yy * 64 + xx];
                if (BN) {
#pragma unroll
                    for (int j = 0; j < 4; ++j) v[j] = v[j] * inv + ad;
                }
            }
            r[rr][gq * 4 + 0] = v[0]; r[rr][gq * 4 + 1] = v[1];
            r[rr][gq * 4 + 2] = v[2]; r[rr][gq * 4 + 3] = v[3];
        }
    }

#pragma unroll
    for (int j = 0; j < 4; ++j) {
        float acc[8] = {};
#pragma unroll
        for (int ky = 0; ky < 3; ++ky) {
#pragma unroll
            for (int kx = 0; kx < 3; ++kx) {
                float ww = w[ky * 3 + kx];
#pragma unroll
                for (int p = 0; p < 8; ++p)
                    acc[p] += ww * r[j + ky][3 + p + kx];
            }
        }
        f32x4 lo = {acc[0], acc[1], acc[2], acc[3]};
        f32x4 hi = {acc[4], acc[5], acc[6], acc[7]};
        *(f32x4*)&Ob[(y0 + j) * 64 + x0]     = lo;
        *(f32x4*)&Ob[(y0 + j) * 64 + x0 + 4] = hi;
    }
}

// ---------------------------------------------------------------------------
// Bilinear align_corners=True resize 64x64 -> 16x16 per channel plane.
// ---------------------------------------------------------------------------
__global__ __launch_bounds__(256) void interp_k(
    const float* __restrict__ T, float* __restrict__ R)
{
    int bc = blockIdx.x;
    const float* Tb = T + (size_t)bc * 4096;
    int p  = threadIdx.x;
    int oy = p >> 4, ox = p & 15;
    const float st = 63.0f / 15.0f;
    float fy = oy * st, fx = ox * st;
    int y0 = (int)floorf(fy); int y1 = min(y0 + 1, 63); float wy = fy - (float)y0;
    int x0 = (int)floorf(fx); int x1 = min(x0 + 1, 63); float wx = fx - (float)x0;
    float v00 = Tb[y0 * 64 + x0], v01 = Tb[y0 * 64 + x1];
    float v10 = Tb[y1 * 64 + x0], v11 = Tb[y1 * 64 + x1];
    R[(size_t)bc * 256 + p] =
        (1.f - wy) * ((1.f - wx) * v00 + wx * v01) +
        wy         * ((1.f - wx) * v10 + wx * v11);
}

// ---------------------------------------------------------------------------
// bf16 MFMA GEMM: Out[b][n][m] = sum_k W[n][k] * A[b][k][m]  (K=256 fixed)
// MODE 0: plain. MODE 1: += X. MODE 2: A'=relu(bn(A)) (channel=k), += X.
// ---------------------------------------------------------------------------
template<int MODE>
__global__ __launch_bounds__(256) void mgemm_k(
    const float* __restrict__ A, const float* __restrict__ W,
    float* __restrict__ Out, const float* __restrict__ X,
    const float* __restrict__ g, const float* __restrict__ be,
    const float* __restrict__ mn, const float* __restrict__ vr,
    int M, int Ntot)
{
    __shared__ short Ws[128 * 256];
    __shared__ short As[128 * 64];
    int b = blockIdx.z, m0 = blockIdx.x * 128, n0 = blockIdx.y * 128;
    int tid = threadIdx.x;
    const float* Ab = A + (size_t)b * 256 * M;

#pragma unroll
    for (int it = 0; it < 32; ++it) {
        int idx = it * 256 + tid;
        int n = idx >> 6, kq = idx & 63;
        f32x4 w4 = *(const f32x4*)&W[(size_t)(n0 + n) * 256 + kq * 4];
        short4v pk = { (short)f2bf(w4[0]), (short)f2bf(w4[1]),
                       (short)f2bf(w4[2]), (short)f2bf(w4[3]) };
        *(short4v*)&Ws[n * 256 + ((kq ^ swz(n)) << 2)] = pk;
    }

    int mg = tid & 31, kg = tid >> 5;
    f32x4 rg[8];
    auto load_tile = [&](int k0) {
#pragma unroll
        for (int half = 0; half < 2; ++half) {
#pragma unroll
            for (int i = 0; i < 4; ++i) {
                int c = k0 + kg * 4 + half * 32 + i;
                f32x4 v = *(const f32x4*)&Ab[(size_t)c * M + m0 + mg * 4];
                if (MODE == 2) {
                    float iv = g[c] * rsqrtf(vr[c] + EPSF);
                    float ad = be[c] - mn[c] * iv;
#pragma unroll
                    for (int j = 0; j < 4; ++j) v[j] = fmaxf(v[j] * iv + ad, 0.f);
                }
                rg[half * 4 + i] = v;
            }
        }
    };
    load_tile(0);

    int w = tid >> 6, lane = tid & 63;
    int wm = w & 1, wn = w >> 1;
    int lg = lane >> 4, lc = lane & 15;
    f32x4 acc[4][4] = {};

    for (int k0 = 0; k0 < 256; k0 += 64) {
        __syncthreads();
#pragma unroll
        for (int half = 0; half < 2; ++half) {
#pragma unroll
            for (int j = 0; j < 4; ++j) {
                int m = mg * 4 + j;
                short4v pk = { (short)f2bf(rg[half * 4 + 0][j]), (short)f2bf(rg[half * 4 + 1][j]),
                               (short)f2bf(rg[half * 4 + 2][j]), (short)f2bf(rg[half * 4 + 3][j]) };
                *(short4v*)&As[m * 64 + (((kg + half * 8) ^ swz(m)) << 2)] = pk;
            }
        }
        __syncthreads();
        if (k0 < 192) load_tile(k0 + 64);
#pragma unroll
        for (int ksl = 0; ksl < 2; ++ksl) {
            short8 wf[4], af[4];
            int gk = (k0 + ksl * 32 + lg * 8) >> 2;
            int ga = (ksl * 32 + lg * 8) >> 2;
#pragma unroll
            for (int nt = 0; nt < 4; ++nt) {
                int n = wn * 64 + nt * 16 + lc;
                wf[nt] = *(const short8*)&Ws[n * 256 + ((gk ^ swz(n)) << 2)];
            }
#pragma unroll
            for (int mt = 0; mt < 4; ++mt) {
                int m = wm * 64 + mt * 16 + lc;
                af[mt] = *(const short8*)&As[m * 64 + ((ga ^ swz(m)) << 2)];
            }
#pragma unroll
            for (int nt = 0; nt < 4; ++nt)
#pragma unroll
                for (int mt = 0; mt < 4; ++mt)
                    acc[nt][mt] = __builtin_amdgcn_mfma_f32_16x16x32_bf16(
                        wf[nt], af[mt], acc[nt][mt], 0, 0, 0);
        }
    }

    size_t ob = (size_t)b * Ntot * M;
#pragma unroll
    for (int nt = 0; nt < 4; ++nt) {
#pragma unroll
        for (int mt = 0; mt < 4; ++mt) {
#pragma unroll
            for (int reg = 0; reg < 4; ++reg) {
                int n = n0 + wn * 64 + nt * 16 + lg * 4 + reg;
                int m = m0 + wm * 64 + mt * 16 + lc;
                size_t addr = ob + (size_t)n * M + m;
                float v = acc[nt][mt][reg];
                if (MODE >= 1) v += X[addr];
                Out[addr] = v;
            }
        }
    }
}

// ---------------------------------------------------------------------------
// MFMA attention; epilogue now stages O-tile in LDS (reusing consumed P area)
// and writes global in coalesced 64B segments.
// ---------------------------------------------------------------------------
__global__ __launch_bounds__(512) void attn_mfma_k(
    const float* __restrict__ Q, const float* __restrict__ KV,
    const float* __restrict__ rel, float* __restrict__ O)
{
    __shared__ unsigned short Ks[256 * 40];
    __shared__ unsigned short Vt[32 * 264];
    __shared__ unsigned short Pw[8 * 16 * 264];
    __shared__ float rels[961];

    int b = blockIdx.z, h = blockIdx.y, chunk = blockIdx.x;
    int tid = threadIdx.x;
    const float* kvb = KV + (size_t)b * 512 * 256;

    for (int idx = tid; idx < 256 * 16; idx += 512) {
        int r = idx & 255, d = (idx >> 8) * 2;
        float a0 = kvb[(size_t)(d * 8 + h) * 256 + r];
        float a1 = kvb[(size_t)((d + 1) * 8 + h) * 256 + r];
        unsigned pk = (unsigned)f2bf(a0) | ((unsigned)f2bf(a1) << 16);
        *(unsigned*)&Ks[r * 40 + d] = pk;
    }
    for (int idx = tid; idx < 32 * 128; idx += 512) {
        int d = idx >> 7, k2 = (idx & 127) * 2;
        float2 v2 = *(const float2*)&kvb[(size_t)(256 + d * 8 + h) * 256 + k2];
        unsigned pk = (unsigned)f2bf(v2.x) | ((unsigned)f2bf(v2.y) << 16);
        *(unsigned*)&Vt[d * 264 + k2] = pk;
    }
    for (int idx = tid; idx < 961; idx += 512) rels[idx] = rel[idx * 8 + h];
    __syncthreads();

    int w = tid >> 6, lane = tid & 63;
    int lg = lane >> 4, lc = lane & 15;
    unsigned short* Pws = Pw + w * 16 * 264;

    short8 kf[16], vf[16];
#pragma unroll
    for (int kt = 0; kt < 16; ++kt)
        kf[kt] = *(const short8*)&Ks[(kt * 16 + lc) * 40 + lg * 8];
#pragma unroll
    for (int f = 0; f < 16; ++f) {
        int ks = f >> 1, nt = f & 1;
        vf[f] = *(const short8*)&Vt[(nt * 16 + lc) * 264 + ks * 32 + lg * 8];
    }

    const float SCALE = 0.17677669529663687f;
    const float* Qb = Q + (size_t)b * 256 * 4096;
    float* Ob = O + (size_t)b * 256 * 4096;
    int rw = chunk * 512 + w * 64;

    for (int mt = 0; mt < 4; ++mt) {
        int rbase = rw + mt * 16;
        int r_a = rbase + lc;
        short8 qf;
#pragma unroll
        for (int j = 0; j < 8; ++j) {
            float qv = Qb[(size_t)((lg * 8 + j) * 8 + h) * 4096 + r_a];
            qf[j] = (short)f2bf(qv);
        }

        f32x4 sacc[16];
#pragma unroll
        for (int kt = 0; kt < 16; ++kt) {
            f32x4 z = {0.f, 0.f, 0.f, 0.f};
            sacc[kt] = __builtin_amdgcn_mfma_f32_16x16x32_bf16(qf, kf[kt], z, 0, 0, 0);
        }

        int ibase[4];
#pragma unroll
        for (int reg = 0; reg < 4; ++reg) {
            int r = rbase + lg * 4 + reg;
            int ay = r >> 8, ax = (r >> 2) & 15;
            ibase[reg] = (ay + 15) * 31 + ax + 15 - lc;
        }
        float mx[4] = {-1e30f, -1e30f, -1e30f, -1e30f};
#pragma unroll
        for (int kt = 0; kt < 16; ++kt) {
            int ib = -kt * 31;
#pragma unroll
            for (int reg = 0; reg < 4; ++reg) {
                float v = (sacc[kt][reg] + rels[ibase[reg] + ib]) * SCALE;
                sacc[kt][reg] = v;
                mx[reg] = fmaxf(mx[reg], v);
            }
        }
#pragma unroll
        for (int off = 1; off < 16; off <<= 1) {
#pragma unroll
            for (int reg = 0; reg < 4; ++reg)
                mx[reg] = fmaxf(mx[reg], __shfl_xor(mx[reg], off));
        }
        float ls[4] = {0.f, 0.f, 0.f, 0.f};
#pragma unroll
        for (int kt = 0; kt < 16; ++kt) {
#pragma unroll
            for (int reg = 0; reg < 4; ++reg) {
                float p = __expf(sacc[kt][reg] - mx[reg]);
                ls[reg] += p;
                Pws[(lg * 4 + reg) * 264 + kt * 16 + lc] = f2bf(p);
            }
        }
#pragma unroll
        for (int off = 1; off < 16; off <<= 1) {
#pragma unroll
            for (int reg = 0; reg < 4; ++reg)
                ls[reg] += __shfl_xor(ls[reg], off);
        }

        f32x4 o0 = {0.f, 0.f, 0.f, 0.f}, o1 = {0.f, 0.f, 0.f, 0.f};
#pragma unroll
        for (int ks = 0; ks < 8; ++ks) {
            short8 pf = *(const short8*)&Pws[lc * 264 + ks * 32 + lg * 8];
            o0 = __builtin_amdgcn_mfma_f32_16x16x32_bf16(pf, vf[ks * 2 + 0], o0, 0, 0, 0);
            o1 = __builtin_amdgcn_mfma_f32_16x16x32_bf16(pf, vf[ks * 2 + 1], o1, 0, 0, 0);
        }

        // stage O tile (16 rows x 32 dims, f32) into consumed P area, then
        // write coalesced (16-lane-contiguous 64B segments)
        float* Owf = (float*)Pws;
#pragma unroll
        for (int reg = 0; reg < 4; ++reg) {
            float rl = 1.f / ls[reg];
            int row = lg * 4 + reg;
            Owf[row * 33 + lc]      = o0[reg] * rl;
            Owf[row * 33 + 16 + lc] = o1[reg] * rl;
        }
#pragma unroll
        for (int i = 0; i < 8; ++i) {
            int d  = (lane >> 4) + 4 * i;
            int rr = lane & 15;
            Ob[(size_t)(d * 8 + h) * 4096 + rbase + rr] = Owf[rr * 33 + d];
        }
    }
}

// ---------------------------------------------------------------------------
extern "C" void kernel_launch(void* const* d_in, const int* in_sizes, int n_in,
                              void* d_out, int out_size, void* d_ws, size_t ws_size,
                              hipStream_t stream)
{
    const float* x       = (const float*)d_in[0];
    const float* bn1_g   = (const float*)d_in[1];
    const float* bn1_b   = (const float*)d_in[2];
    const float* bn1_m   = (const float*)d_in[3];
    const float* bn1_v   = (const float*)d_in[4];
    const float* qkv_dw  = (const float*)d_in[5];
    const float* qkv_pw  = (const float*)d_in[6];
    const float* out_dw  = (const float*)d_in[7];
    const float* out_pw  = (const float*)d_in[8];
    const float* rel     = (const float*)d_in[9];
    const float* bn2_g   = (const float*)d_in[10];
    const float* bn2_b   = (const float*)d_in[11];
    const float* bn2_m   = (const float*)d_in[12];
    const float* bn2_v   = (const float*)d_in[13];
    const float* mlp_w   = (const float*)d_in[14];
    float* out = (float*)d_out;

    float* ws = (float*)d_ws;
    float* t   = ws;                           // BUF0: t / o / a
    float* q   = ws + (size_t)8 * 1024 * 1024; // BUF1: q / t2
    float* tr  = ws + (size_t)16 * 1024 * 1024;
    float* kv  = tr + 524288;
    float* o   = t;
    float* t2  = q;
    float* a   = t;

    // 1. t = dwconv3(bn1(x))
    dwconv_k<true><<<dim3(1024), 256, 0, stream>>>(
        x, qkv_dw, bn1_g, bn1_b, bn1_m, bn1_v, t);

    // 2. q = qkv_pw[0:256] * t     [B,256,4096]
    mgemm_k<0><<<dim3(32, 2, 8), 256, 0, stream>>>(
        t, qkv_pw, q, nullptr, nullptr, nullptr, nullptr, nullptr,
        4096, 256);

    // 3. tr = interp(t) -> 16x16
    interp_k<<<dim3(2048), 256, 0, stream>>>(t, tr);

    // 4. kv = qkv_pw[256:768] * tr   [B,512,256]
    mgemm_k<0><<<dim3(2, 4, 8), 256, 0, stream>>>(
        tr, qkv_pw + 256 * 256, kv, nullptr, nullptr, nullptr, nullptr, nullptr,
        256, 512);

    // 5. o = MFMA attention(q, kv, rel)   [B,256,4096]   (overwrites t)
    attn_mfma_k<<<dim3(8, 8, 8), 512, 0, stream>>>(q, kv, rel, o);

    // 6. t2 = dwconv3(o)            (overwrites q)
    dwconv_k<false><<<dim3(1024), 256, 0, stream>>>(
        o, out_dw, nullptr, nullptr, nullptr, nullptr, t2);

    // 7. a = out_pw * t2 + x        (overwrites o)
    mgemm_k<1><<<dim3(32, 2, 8), 256, 0, stream>>>(
        t2, out_pw, a, x, nullptr, nullptr, nullptr, nullptr,
        4096, 256);

    // 8. out = mlp_w * relu(bn2(a)) + a
    mgemm_k<2><<<dim3(32, 2, 8), 256, 0, stream>>>(
        a, mlp_w, out, a, bn2_g, bn2_b, bn2_m, bn2_v,
        4096, 256);
}

// Round 5
// 148.856 us; speedup vs baseline: 4.1861x; 1.0002x over previous
//
#include <hip/hip_runtime.h>
#include <math.h>

#define EPSF 1e-5f

typedef float f32x4 __attribute__((ext_vector_type(4)));
typedef short short8 __attribute__((ext_vector_type(8)));
typedef short short4v __attribute__((ext_vector_type(4)));

static __device__ __forceinline__ unsigned short f2bf(float f) {
    unsigned u = __float_as_uint(f);
    u = (u + 0x7FFF + ((u >> 16) & 1)) >> 16;
    return (unsigned short)u;
}

// XOR-swizzle: spreads 8-byte granules of a row across banks; keeps 16B pairs.
static __device__ __forceinline__ int swz(int r) { return ((r ^ (r >> 2)) & 7) << 1; }

// ---------------------------------------------------------------------------
// Depthwise 3x3 conv (SAME), vectorized: each thread computes a 4x8 tile.
// ---------------------------------------------------------------------------
template<bool BN>
__global__ __launch_bounds__(256) void dwconv_k(
    const float* __restrict__ X, const float* __restrict__ DW,
    const float* __restrict__ g, const float* __restrict__ be,
    const float* __restrict__ mn, const float* __restrict__ vr,
    float* __restrict__ Out)
{
    int tid = threadIdx.x;
    int plane = blockIdx.x * 2 + (tid >> 7);
    int c = plane & 255;
    float inv = 1.f, ad = 0.f;
    if (BN) {
        inv = g[c] * rsqrtf(vr[c] + EPSF);
        ad  = be[c] - mn[c] * inv;
    }
    float w[9];
#pragma unroll
    for (int i = 0; i < 9; ++i) w[i] = DW[c * 9 + i];
    const float* Xb = X + (size_t)plane * 4096;
    float* Ob = Out + (size_t)plane * 4096;
    int u  = tid & 127;
    int y0 = (u >> 3) * 4;
    int x0 = (u & 7) * 8;

    float r[6][16];
#pragma unroll
    for (int rr = 0; rr < 6; ++rr) {
        int yy = y0 + rr - 1;
        bool rv = (unsigned)yy < 64u;
#pragma unroll
        for (int gq = 0; gq < 4; ++gq) {
            int xx = x0 - 4 + gq * 4;
            f32x4 v = {0.f, 0.f, 0.f, 0.f};
            if (rv && (unsigned)xx < 64u) {
                v = *(const f32x4*)&Xb[yy * 64 + xx];
                if (BN) {
#pragma unroll
                    for (int j = 0; j < 4; ++j) v[j] = v[j] * inv + ad;
                }
            }
            r[rr][gq * 4 + 0] = v[0]; r[rr][gq * 4 + 1] = v[1];
            r[rr][gq * 4 + 2] = v[2]; r[rr][gq * 4 + 3] = v[3];
        }
    }

#pragma unroll
    for (int j = 0; j < 4; ++j) {
        float acc[8] = {};
#pragma unroll
        for (int ky = 0; ky < 3; ++ky) {
#pragma unroll
            for (int kx = 0; kx < 3; ++kx) {
                float ww = w[ky * 3 + kx];
#pragma unroll
                for (int p = 0; p < 8; ++p)
                    acc[p] += ww * r[j + ky][3 + p + kx];
            }
        }
        f32x4 lo = {acc[0], acc[1], acc[2], acc[3]};
        f32x4 hi = {acc[4], acc[5], acc[6], acc[7]};
        *(f32x4*)&Ob[(y0 + j) * 64 + x0]     = lo;
        *(f32x4*)&Ob[(y0 + j) * 64 + x0 + 4] = hi;
    }
}

// ---------------------------------------------------------------------------
// Bilinear align_corners=True resize 64x64 -> 16x16 per channel plane.
// ---------------------------------------------------------------------------
__global__ __launch_bounds__(256) void interp_k(
    const float* __restrict__ T, float* __restrict__ R)
{
    int bc = blockIdx.x;
    const float* Tb = T + (size_t)bc * 4096;
    int p  = threadIdx.x;
    int oy = p >> 4, ox = p & 15;
    const float st = 63.0f / 15.0f;
    float fy = oy * st, fx = ox * st;
    int y0 = (int)floorf(fy); int y1 = min(y0 + 1, 63); float wy = fy - (float)y0;
    int x0 = (int)floorf(fx); int x1 = min(x0 + 1, 63); float wx = fx - (float)x0;
    float v00 = Tb[y0 * 64 + x0], v01 = Tb[y0 * 64 + x1];
    float v10 = Tb[y1 * 64 + x0], v11 = Tb[y1 * 64 + x1];
    R[(size_t)bc * 256 + p] =
        (1.f - wy) * ((1.f - wx) * v00 + wx * v01) +
        wy         * ((1.f - wx) * v10 + wx * v11);
}

// ---------------------------------------------------------------------------
// bf16 MFMA GEMM: Out[b][n][m] = sum_k W[n][k] * A[b][k][m]  (K=256 fixed)
// MODE 0: plain. MODE 1: += X. MODE 2: A'=relu(bn(A)) (channel=k), += X.
// OB: write output as bf16 (ushort) instead of f32.
// ---------------------------------------------------------------------------
template<int MODE, bool OB>
__global__ __launch_bounds__(256) void mgemm_k(
    const float* __restrict__ A, const float* __restrict__ W,
    float* __restrict__ Out, const float* __restrict__ X,
    const float* __restrict__ g, const float* __restrict__ be,
    const float* __restrict__ mn, const float* __restrict__ vr,
    int M, int Ntot)
{
    __shared__ short Ws[128 * 256];
    __shared__ short As[128 * 64];
    int b = blockIdx.z, m0 = blockIdx.x * 128, n0 = blockIdx.y * 128;
    int tid = threadIdx.x;
    const float* Ab = A + (size_t)b * 256 * M;

#pragma unroll
    for (int it = 0; it < 32; ++it) {
        int idx = it * 256 + tid;
        int n = idx >> 6, kq = idx & 63;
        f32x4 w4 = *(const f32x4*)&W[(size_t)(n0 + n) * 256 + kq * 4];
        short4v pk = { (short)f2bf(w4[0]), (short)f2bf(w4[1]),
                       (short)f2bf(w4[2]), (short)f2bf(w4[3]) };
        *(short4v*)&Ws[n * 256 + ((kq ^ swz(n)) << 2)] = pk;
    }

    int mg = tid & 31, kg = tid >> 5;
    f32x4 rg[8];
    auto load_tile = [&](int k0) {
#pragma unroll
        for (int half = 0; half < 2; ++half) {
#pragma unroll
            for (int i = 0; i < 4; ++i) {
                int c = k0 + kg * 4 + half * 32 + i;
                f32x4 v = *(const f32x4*)&Ab[(size_t)c * M + m0 + mg * 4];
                if (MODE == 2) {
                    float iv = g[c] * rsqrtf(vr[c] + EPSF);
                    float ad = be[c] - mn[c] * iv;
#pragma unroll
                    for (int j = 0; j < 4; ++j) v[j] = fmaxf(v[j] * iv + ad, 0.f);
                }
                rg[half * 4 + i] = v;
            }
        }
    };
    load_tile(0);

    int w = tid >> 6, lane = tid & 63;
    int wm = w & 1, wn = w >> 1;
    int lg = lane >> 4, lc = lane & 15;
    f32x4 acc[4][4] = {};

    for (int k0 = 0; k0 < 256; k0 += 64) {
        __syncthreads();
#pragma unroll
        for (int half = 0; half < 2; ++half) {
#pragma unroll
            for (int j = 0; j < 4; ++j) {
                int m = mg * 4 + j;
                short4v pk = { (short)f2bf(rg[half * 4 + 0][j]), (short)f2bf(rg[half * 4 + 1][j]),
                               (short)f2bf(rg[half * 4 + 2][j]), (short)f2bf(rg[half * 4 + 3][j]) };
                *(short4v*)&As[m * 64 + (((kg + half * 8) ^ swz(m)) << 2)] = pk;
            }
        }
        __syncthreads();
        if (k0 < 192) load_tile(k0 + 64);
#pragma unroll
        for (int ksl = 0; ksl < 2; ++ksl) {
            short8 wf[4], af[4];
            int gk = (k0 + ksl * 32 + lg * 8) >> 2;
            int ga = (ksl * 32 + lg * 8) >> 2;
#pragma unroll
            for (int nt = 0; nt < 4; ++nt) {
                int n = wn * 64 + nt * 16 + lc;
                wf[nt] = *(const short8*)&Ws[n * 256 + ((gk ^ swz(n)) << 2)];
            }
#pragma unroll
            for (int mt = 0; mt < 4; ++mt) {
                int m = wm * 64 + mt * 16 + lc;
                af[mt] = *(const short8*)&As[m * 64 + ((ga ^ swz(m)) << 2)];
            }
#pragma unroll
            for (int nt = 0; nt < 4; ++nt)
#pragma unroll
                for (int mt = 0; mt < 4; ++mt)
                    acc[nt][mt] = __builtin_amdgcn_mfma_f32_16x16x32_bf16(
                        wf[nt], af[mt], acc[nt][mt], 0, 0, 0);
        }
    }

    size_t ob = (size_t)b * Ntot * M;
#pragma unroll
    for (int nt = 0; nt < 4; ++nt) {
#pragma unroll
        for (int mt = 0; mt < 4; ++mt) {
#pragma unroll
            for (int reg = 0; reg < 4; ++reg) {
                int n = n0 + wn * 64 + nt * 16 + lg * 4 + reg;
                int m = m0 + wm * 64 + mt * 16 + lc;
                size_t addr = ob + (size_t)n * M + m;
                float v = acc[nt][mt][reg];
                if (MODE >= 1) v += X[addr];
                if (OB) ((unsigned short*)Out)[addr] = f2bf(v);
                else    Out[addr] = v;
            }
        }
    }
}

// ---------------------------------------------------------------------------
// MFMA attention, swapped-QK layout: S[key][qrow], P exchanged in-register.
// Q: bf16 [B,256ch,4096] (ch = d*8+h), KV: bf16 [B,512,256],
// rel: f32 [961,8], O: f32 [B,256,4096].
// grid (8, H, B), 512 threads = 8 waves, each wave: 64 q-rows (4 m-tiles).
// ---------------------------------------------------------------------------
__global__ __launch_bounds__(512) void attn_mfma_k(
    const unsigned short* __restrict__ Q, const unsigned short* __restrict__ KV,
    const float* __restrict__ rel, float* __restrict__ O)
{
    __shared__ unsigned short Ks[256 * 40];   // [key][dim], pad 40  (20.0 KB)
    __shared__ unsigned short Vt[32 * 264];   // [dim][key], pad 264 (16.9 KB)
    __shared__ float rels[961];               // (3.8 KB)

    int b = blockIdx.z, h = blockIdx.y, chunk = blockIdx.x;
    int tid = threadIdx.x;
    const unsigned short* kvb = KV + (size_t)b * 512 * 256;

    for (int idx = tid; idx < 256 * 32; idx += 512) {
        int r = idx & 255, d = idx >> 8;
        Ks[r * 40 + d] = kvb[(size_t)(d * 8 + h) * 256 + r];
    }
    for (int idx = tid; idx < 32 * 256; idx += 512) {
        int d = idx >> 8, k = idx & 255;
        Vt[d * 264 + k] = kvb[(size_t)(256 + d * 8 + h) * 256 + k];
    }
    for (int idx = tid; idx < 961; idx += 512) rels[idx] = rel[idx * 8 + h];
    __syncthreads();

    int w = tid >> 6, lane = tid & 63;
    int lg = lane >> 4, lc = lane & 15;

    const float SCALE = 0.17677669529663687f;  // 32^-0.5
    const unsigned short* Qb = Q + (size_t)b * 256 * 4096;
    float* Ob = O + (size_t)b * 256 * 4096;
    int rw = chunk * 512 + w * 64;

    // P-exchange source lanes: lg' = (2lg)&3 (j<4) and +1 (j>=4), same lc.
    int s1 = (((lane >> 4) & 1) << 5) + lc;   // lg'*16 + lc, lg'=(lg&1)*2
    int s2 = s1 + 16;
    bool useOdd = (lg >> 1) != 0;

    for (int mt = 0; mt < 4; ++mt) {
        int rbase = rw + mt * 16;
        int r_a = rbase + lc;

        // Q B-fragment: col = qrow (lc), k = dim lg*8+j
        short8 qf;
#pragma unroll
        for (int j = 0; j < 8; ++j)
            qf[j] = (short)Qb[(size_t)((lg * 8 + j) * 8 + h) * 4096 + r_a];

        // QK^T swapped: D[key][qrow]; lane holds keys kt*16+lg*4+reg, qrow lc
        f32x4 sacc[16];
#pragma unroll
        for (int kt = 0; kt < 16; ++kt) {
            short8 kf = *(const short8*)&Ks[(kt * 16 + lc) * 40 + lg * 8];
            f32x4 z = {0.f, 0.f, 0.f, 0.f};
            sacc[kt] = __builtin_amdgcn_mfma_f32_16x16x32_bf16(kf, qf, z, 0, 0, 0);
        }

        // bias + scale + row max (row = q-row = lc across lg,kt,reg)
        int ay = r_a >> 8, ax = (r_a >> 2) & 15;
        int ibase = (ay + 15) * 31 + ax + 15 - lg * 4;
        float mx = -1e30f;
#pragma unroll
        for (int kt = 0; kt < 16; ++kt) {
            int ib = ibase - 31 * kt;
#pragma unroll
            for (int reg = 0; reg < 4; ++reg) {
                float v = (sacc[kt][reg] + rels[ib - reg]) * SCALE;
                sacc[kt][reg] = v;
                mx = fmaxf(mx, v);
            }
        }
        mx = fmaxf(mx, __shfl_xor(mx, 16));
        mx = fmaxf(mx, __shfl_xor(mx, 32));

        // exp, row sum, pack P to bf16 pairs
        float ls = 0.f;
        unsigned plo[16], phi[16];
#pragma unroll
        for (int kt = 0; kt < 16; ++kt) {
            float p0 = __expf(sacc[kt][0] - mx);
            float p1 = __expf(sacc[kt][1] - mx);
            float p2 = __expf(sacc[kt][2] - mx);
            float p3 = __expf(sacc[kt][3] - mx);
            ls += (p0 + p1) + (p2 + p3);
            plo[kt] = (unsigned)f2bf(p0) | ((unsigned)f2bf(p1) << 16);
            phi[kt] = (unsigned)f2bf(p2) | ((unsigned)f2bf(p3) << 16);
        }
        ls += __shfl_xor(ls, 16);
        ls += __shfl_xor(ls, 32);

        // PV: D[d][qrow]; B-frag pf[j] = P[ks*32+lg*8+j][lc] via lane exchange
        f32x4 o0 = {0.f, 0.f, 0.f, 0.f}, o1 = {0.f, 0.f, 0.f, 0.f};
#pragma unroll
        for (int ks = 0; ks < 8; ++ks) {
            int eA = __shfl((int)plo[2 * ks], s1), oA = __shfl((int)plo[2 * ks + 1], s1);
            int eB = __shfl((int)phi[2 * ks], s1), oB = __shfl((int)phi[2 * ks + 1], s1);
            int eC = __shfl((int)plo[2 * ks], s2), oC = __shfl((int)plo[2 * ks + 1], s2);
            int eD = __shfl((int)phi[2 * ks], s2), oD = __shfl((int)phi[2 * ks + 1], s2);
            int4 pi = { useOdd ? oA : eA, useOdd ? oB : eB,
                        useOdd ? oC : eC, useOdd ? oD : eD };
            short8 pf = *(short8*)&pi;
            short8 v0 = *(const short8*)&Vt[lc * 264 + ks * 32 + lg * 8];
            short8 v1 = *(const short8*)&Vt[(16 + lc) * 264 + ks * 32 + lg * 8];
            o0 = __builtin_amdgcn_mfma_f32_16x16x32_bf16(v0, pf, o0, 0, 0, 0);
            o1 = __builtin_amdgcn_mfma_f32_16x16x32_bf16(v1, pf, o1, 0, 0, 0);
        }

        // epilogue: lane holds dims d=lg*4+reg (o0) / 16+lg*4+reg (o1), qrow=lc
        float rl = 1.f / ls;
#pragma unroll
        for (int reg = 0; reg < 4; ++reg) {
            int d0 = lg * 4 + reg;
            Ob[(size_t)(d0 * 8 + h) * 4096 + rbase + lc]        = o0[reg] * rl;
            Ob[(size_t)((16 + d0) * 8 + h) * 4096 + rbase + lc] = o1[reg] * rl;
        }
    }
}

// ---------------------------------------------------------------------------
extern "C" void kernel_launch(void* const* d_in, const int* in_sizes, int n_in,
                              void* d_out, int out_size, void* d_ws, size_t ws_size,
                              hipStream_t stream)
{
    const float* x       = (const float*)d_in[0];
    const float* bn1_g   = (const float*)d_in[1];
    const float* bn1_b   = (const float*)d_in[2];
    const float* bn1_m   = (const float*)d_in[3];
    const float* bn1_v   = (const float*)d_in[4];
    const float* qkv_dw  = (const float*)d_in[5];
    const float* qkv_pw  = (const float*)d_in[6];
    const float* out_dw  = (const float*)d_in[7];
    const float* out_pw  = (const float*)d_in[8];
    const float* rel     = (const float*)d_in[9];
    const float* bn2_g   = (const float*)d_in[10];
    const float* bn2_b   = (const float*)d_in[11];
    const float* bn2_m   = (const float*)d_in[12];
    const float* bn2_v   = (const float*)d_in[13];
    const float* mlp_w   = (const float*)d_in[14];
    float* out = (float*)d_out;

    float* ws = (float*)d_ws;
    float* t   = ws;                           // BUF0: t / o / a (f32, 8M fl)
    float* q   = ws + (size_t)8 * 1024 * 1024; // BUF1: q(bf16) / t2(f32)
    float* tr  = ws + (size_t)16 * 1024 * 1024;
    float* kv  = tr + 524288;                  // bf16 region
    float* o   = t;
    float* t2  = q;
    float* a   = t;

    // 1. t = dwconv3(bn1(x))
    dwconv_k<true><<<dim3(1024), 256, 0, stream>>>(
        x, qkv_dw, bn1_g, bn1_b, bn1_m, bn1_v, t);

    // 2. q = qkv_pw[0:256] * t     bf16 [B,256,4096]
    mgemm_k<0, true><<<dim3(32, 2, 8), 256, 0, stream>>>(
        t, qkv_pw, q, nullptr, nullptr, nullptr, nullptr, nullptr,
        4096, 256);

    // 3. tr = interp(t) -> 16x16
    interp_k<<<dim3(2048), 256, 0, stream>>>(t, tr);

    // 4. kv = qkv_pw[256:768] * tr   bf16 [B,512,256]
    mgemm_k<0, true><<<dim3(2, 4, 8), 256, 0, stream>>>(
        tr, qkv_pw + 256 * 256, kv, nullptr, nullptr, nullptr, nullptr, nullptr,
        256, 512);

    // 5. o = MFMA attention(q, kv, rel)   f32 [B,256,4096]  (overwrites t)
    attn_mfma_k<<<dim3(8, 8, 8), 512, 0, stream>>>(
        (const unsigned short*)q, (const unsigned short*)kv, rel, o);

    // 6. t2 = dwconv3(o)            (overwrites q)
    dwconv_k<false><<<dim3(1024), 256, 0, stream>>>(
        o, out_dw, nullptr, nullptr, nullptr, nullptr, t2);

    // 7. a = out_pw * t2 + x        (overwrites o)
    mgemm_k<1, false><<<dim3(32, 2, 8), 256, 0, stream>>>(
        t2, out_pw, a, x, nullptr, nullptr, nullptr, nullptr,
        4096, 256);

    // 8. out = mlp_w * relu(bn2(a)) + a
    mgemm_k<2, false><<<dim3(32, 2, 8), 256, 0, stream>>>(
        a, mlp_w, out, a, bn2_g, bn2_b, bn2_m, bn2_v,
        4096, 256);
}